// Round 3
// baseline (1295.120 us; speedup 1.0000x reference)
//
#include <hip/hip_runtime.h>
#include <math.h>

#define NPERM 24
#define ND 256
#define RPB 48            // rows per block (48 | 576, one batch elem per block)
#define RPW 12            // rows per wave (4 waves)
#define ROWS_PER_B 576
#define BATCH 512
#define TOTAL_ROWS (BATCH * ROWS_PER_B)
#define NBLOCKS (TOTAL_ROWS / RPB)   // 6144

// itertools.permutations(range(4)) — lexicographic order, with parity signs
__constant__ int c_P[NPERM * 4] = {
    0,1,2,3, 0,1,3,2, 0,2,1,3, 0,2,3,1, 0,3,1,2, 0,3,2,1,
    1,0,2,3, 1,0,3,2, 1,2,0,3, 1,2,3,0, 1,3,0,2, 1,3,2,0,
    2,0,1,3, 2,0,3,1, 2,1,0,3, 2,1,3,0, 2,3,0,1, 2,3,1,0,
    3,0,1,2, 3,0,2,1, 3,1,0,2, 3,1,2,0, 3,2,0,1, 3,2,1,0
};
__constant__ float c_S[NPERM] = {
     1.f,-1.f,-1.f, 1.f, 1.f,-1.f,
    -1.f, 1.f, 1.f,-1.f,-1.f, 1.f,
     1.f,-1.f,-1.f, 1.f, 1.f,-1.f,
    -1.f, 1.f, 1.f,-1.f,-1.f, 1.f
};

__global__ __launch_bounds__(256, 2)
void fused_resnet(const float* __restrict__ x1, const float* __restrict__ x2,
                  const float* __restrict__ W0, const float* __restrict__ b0,
                  const float* __restrict__ W1, const float* __restrict__ b1,
                  const float* __restrict__ W2, const float* __restrict__ b2,
                  const float* __restrict__ Wf, const float* __restrict__ bf,
                  double* __restrict__ anti)
{
    __shared__ float sY[RPB * ND];     // 48 KB activations (f32 storage, like np/jax)
    __shared__ float sStage[4096];     // 16 KB: W tile; layer0 also feats at [2048..]
    const int t   = threadIdx.x;
    const int tc  = t & 63;            // col group: cols 4*tc..4*tc+3
    const int tr  = t >> 6;            // wave id: rows 12*tr..12*tr+11
    const int gr0 = blockIdx.x * RPB;
    const int b   = gr0 / ROWS_PER_B;

    // ---- build features into sStage[2048 + lr*24 + c] ----
    for (int e = t; e < RPB * 24; e += 256) {
        int lr = e / 24, c = e % 24;
        int pp = (gr0 + lr) % ROWS_PER_B;
        float v;
        if (c < 12) {
            int p1 = pp / 24;
            v = x1[b * 12 + c_P[p1 * 4 + c / 3] * 3 + (c % 3)];
        } else {
            int p2 = pp % 24; int cc = c - 12;
            v = x2[b * 12 + c_P[p2 * 4 + cc / 3] * 3 + (cc % 3)];
        }
        sStage[2048 + e] = v;
    }

    float acc[RPW][4];   // fp32 accumulators, single sequential chain over K (np-like)

    // ---------- layer 0: 24 -> 256, tanh, no residual ----------
    #pragma unroll
    for (int r = 0; r < RPW; ++r) { acc[r][0]=0.f; acc[r][1]=0.f; acc[r][2]=0.f; acc[r][3]=0.f; }
    for (int kt = 0; kt < 24; kt += 8) {
        __syncthreads();
        {   // stage W0 rows [kt, kt+8): 2048 contiguous floats
            const float4* src = (const float4*)(W0 + kt * ND);
            float4* dst = (float4*)sStage;
            for (int i = t; i < (8 * ND) / 4; i += 256) dst[i] = src[i];
        }
        __syncthreads();
        #pragma unroll
        for (int k4 = 0; k4 < 2; ++k4) {
            float w[4][4];
            #pragma unroll
            for (int k = 0; k < 4; ++k) {
                float4 wv = *(const float4*)&sStage[(k4 * 4 + k) * ND + 4 * tc];
                w[k][0]=wv.x; w[k][1]=wv.y; w[k][2]=wv.z; w[k][3]=wv.w;
            }
            #pragma unroll
            for (int r = 0; r < RPW; ++r) {
                float4 yv = *(const float4*)&sStage[2048 + (tr * RPW + r) * 24 + kt + k4 * 4];
                float yk[4] = {yv.x, yv.y, yv.z, yv.w};
                #pragma unroll
                for (int k = 0; k < 4; ++k)
                    #pragma unroll
                    for (int c = 0; c < 4; ++c)
                        acc[r][c] = fmaf(yk[k], w[k][c], acc[r][c]);
            }
        }
    }
    {
        float4 bv = *(const float4*)&b0[4 * tc];
        float bb[4] = {bv.x, bv.y, bv.z, bv.w};
        __syncthreads();
        #pragma unroll
        for (int r = 0; r < RPW; ++r) {
            float4 o;
            o.x = tanhf(acc[r][0] + bb[0]);
            o.y = tanhf(acc[r][1] + bb[1]);
            o.z = tanhf(acc[r][2] + bb[2]);
            o.w = tanhf(acc[r][3] + bb[3]);
            *(float4*)&sY[(tr * RPW + r) * ND + 4 * tc] = o;
        }
        __syncthreads();
    }

    // ---------- layers 1,2: 256 -> 256, tanh + residual ----------
    #pragma unroll 1
    for (int layer = 0; layer < 2; ++layer) {
        const float* W   = layer ? W2 : W1;
        const float* bbp = layer ? b2 : b1;
        #pragma unroll
        for (int r = 0; r < RPW; ++r) { acc[r][0]=0.f; acc[r][1]=0.f; acc[r][2]=0.f; acc[r][3]=0.f; }
        for (int kt = 0; kt < ND; kt += 16) {
            __syncthreads();
            {   // stage W rows [kt, kt+16): 4096 contiguous floats
                const float4* src = (const float4*)(W + kt * ND);
                float4* dst = (float4*)sStage;
                #pragma unroll
                for (int i = 0; i < 4; ++i) dst[t + i * 256] = src[t + i * 256];
            }
            __syncthreads();
            #pragma unroll
            for (int k4 = 0; k4 < 4; ++k4) {
                float w[4][4];
                #pragma unroll
                for (int k = 0; k < 4; ++k) {
                    float4 wv = *(const float4*)&sStage[(k4 * 4 + k) * ND + 4 * tc];
                    w[k][0]=wv.x; w[k][1]=wv.y; w[k][2]=wv.z; w[k][3]=wv.w;
                }
                #pragma unroll
                for (int r = 0; r < RPW; ++r) {
                    float4 yv = *(const float4*)&sY[(tr * RPW + r) * ND + kt + k4 * 4];
                    float yk[4] = {yv.x, yv.y, yv.z, yv.w};
                    #pragma unroll
                    for (int k = 0; k < 4; ++k)
                        #pragma unroll
                        for (int c = 0; c < 4; ++c)
                            acc[r][c] = fmaf(yk[k], w[k][c], acc[r][c]);
                }
            }
        }
        // epilogue: bias + tanh + residual (all fp32, np order)
        float4 bv = *(const float4*)&bbp[4 * tc];
        float bb[4] = {bv.x, bv.y, bv.z, bv.w};
        float ny[RPW][4];
        #pragma unroll
        for (int r = 0; r < RPW; ++r) {
            float4 yo = *(const float4*)&sY[(tr * RPW + r) * ND + 4 * tc];
            float yov[4] = {yo.x, yo.y, yo.z, yo.w};
            #pragma unroll
            for (int c = 0; c < 4; ++c)
                ny[r][c] = tanhf(acc[r][c] + bb[c]) + yov[c];
        }
        __syncthreads();   // all reads of old sY complete before overwrite
        #pragma unroll
        for (int r = 0; r < RPW; ++r) {
            float4 o; o.x = ny[r][0]; o.y = ny[r][1]; o.z = ny[r][2]; o.w = ny[r][3];
            *(float4*)&sY[(tr * RPW + r) * ND + 4 * tc] = o;
        }
        __syncthreads();
    }

    // ---------- head ----------
    // Per-row fp32 sequential FMA chain over all 256 elements (mirrors np's
    // per-row gemv rounding), then EXACT f64 signed sum across rows.
    if (t < 64) {   // stage Wf into sStage[0..255]
        ((float4*)sStage)[t] = ((const float4*)Wf)[t];
    }
    __syncthreads();
    double contrib = 0.0;
    if (tc < RPW) {
        int row = tr * RPW + tc;
        const float* yrow = &sY[row * ND];
        float f = 0.f;
        #pragma unroll 8
        for (int k = 0; k < ND; ++k) f = fmaf(yrow[k], sStage[k], f);
        f += bf[0];
        int pp = (gr0 + row) % ROWS_PER_B;
        double s = (double)(c_S[pp / 24] * c_S[pp % 24]);
        contrib = s * (double)f;
    }
    #pragma unroll
    for (int off = 32; off > 0; off >>= 1) contrib += __shfl_xor(contrib, off, 64);
    if (tc == 0) atomicAdd(&anti[b], contrib);
}

__global__ void finalize_log(const double* __restrict__ anti, float* __restrict__ out) {
    int i = blockIdx.x * 256 + threadIdx.x;
    if (i < BATCH) out[i] = (float)log(fabs(anti[i]));
}

extern "C" void kernel_launch(void* const* d_in, const int* in_sizes, int n_in,
                              void* d_out, int out_size, void* d_ws, size_t ws_size,
                              hipStream_t stream) {
    const float* x1 = (const float*)d_in[0];
    const float* x2 = (const float*)d_in[1];
    const float* W0 = (const float*)d_in[2];
    const float* b0 = (const float*)d_in[3];
    const float* W1 = (const float*)d_in[4];
    const float* b1 = (const float*)d_in[5];
    const float* W2 = (const float*)d_in[6];
    const float* b2 = (const float*)d_in[7];
    const float* Wf = (const float*)d_in[8];
    const float* bf = (const float*)d_in[9];
    double* anti = (double*)d_ws;                   // 512 doubles of scratch
    float* out   = (float*)d_out;

    hipMemsetAsync(anti, 0, BATCH * sizeof(double), stream);
    fused_resnet<<<NBLOCKS, 256, 0, stream>>>(x1, x2, W0, b0, W1, b1, W2, b2, Wf, bf, anti);
    finalize_log<<<(BATCH + 255) / 256, 256, 0, stream>>>(anti, out);
}